// Round 3
// baseline (987.743 us; speedup 1.0000x reference)
//
#include <hip/hip_runtime.h>
#include <hip/hip_bf16.h>
#include <math.h>

// ---------------------------------------------------------------------------
// MHLA: out, l_kv = MLA(x, cache, W_kv, W_q, W_lq, W_o)
//   l_kv_new = x @ W_kv ; lq = x @ (W_q @ W_lq)  [folded]
//   l_kv = concat(cache, l_kv_new)
//   ctx  = softmax(lq·l_kv^T/sqrt(512))·l_kv     [flash, T=8192, split-T x4]
//   out  = ctx @ W_o
// fp16 MFMA everywhere (f32 accum). d_out's "out" region doubles as scratch.
// ---------------------------------------------------------------------------

typedef _Float16 f16x8 __attribute__((ext_vector_type(8)));
typedef _Float16 f16x4 __attribute__((ext_vector_type(4)));
typedef float    f32x4 __attribute__((ext_vector_type(4)));
typedef float    f32x8 __attribute__((ext_vector_type(8)));

// ---------------------------- elementwise converts -------------------------

__global__ __launch_bounds__(256) void k_cvt(const float* __restrict__ in,
                                             _Float16* __restrict__ out, int n4) {
  int i = blockIdx.x * blockDim.x + threadIdx.x;
  int st = gridDim.x * blockDim.x;
  for (; i < n4; i += st) {
    f32x4 v = reinterpret_cast<const f32x4*>(in)[i];
    reinterpret_cast<f16x4*>(out)[i] = __builtin_convertvector(v, f16x4);
  }
}

// cache (2,4096,512) -> l_kv f32 out rows [b*8192 + t] and fp16 copy
__global__ __launch_bounds__(256) void k_cache(const float* __restrict__ cache,
                                               float* __restrict__ lkv_f32,
                                               _Float16* __restrict__ lkv16, int n4) {
  int i = blockIdx.x * blockDim.x + threadIdx.x;
  int st = gridDim.x * blockDim.x;
  for (; i < n4; i += st) {
    f32x4 v = reinterpret_cast<const f32x4*>(cache)[i];
    int e = i << 2;
    int b = e >> 21;                 // 4096*512 = 2^21
    int dst = e + (b << 21);         // batch stride in l_kv is 2^22
    *reinterpret_cast<f32x4*>(lkv_f32 + dst) = v;
    *reinterpret_cast<f16x4*>(lkv16 + dst) = __builtin_convertvector(v, f16x4);
  }
}

// transpose+convert: in f32 (R x C) -> out fp16 (C x R)
__global__ __launch_bounds__(256) void k_tc(const float* __restrict__ in,
                                            _Float16* __restrict__ out, int R, int C) {
  __shared__ float t[32][33];
  const int c0 = blockIdx.x << 5, r0 = blockIdx.y << 5;
  const int tid = threadIdx.x;
  {
    int r = tid >> 3, c4 = (tid & 7) << 2;
    f32x4 v = *reinterpret_cast<const f32x4*>(&in[(long)(r0 + r) * C + c0 + c4]);
    t[r][c4] = v[0]; t[r][c4 + 1] = v[1]; t[r][c4 + 2] = v[2]; t[r][c4 + 3] = v[3];
  }
  __syncthreads();
  {
    int c = tid >> 3, r4 = (tid & 7) << 2;
    f16x4 o = {(_Float16)t[r4][c], (_Float16)t[r4 + 1][c],
               (_Float16)t[r4 + 2][c], (_Float16)t[r4 + 3][c]};
    *reinterpret_cast<f16x4*>(&out[(long)(c0 + c) * R + r0 + r4]) = o;
  }
}

// transpose fp16: in (R x C) -> out (C x R)
__global__ __launch_bounds__(256) void k_tb(const _Float16* __restrict__ in,
                                            _Float16* __restrict__ out, int R, int C) {
  __shared__ _Float16 t[32][36];
  const int c0 = blockIdx.x << 5, r0 = blockIdx.y << 5;
  const int tid = threadIdx.x;
  {
    int r = tid >> 3, c4 = (tid & 7) << 2;
    f16x4 v = *reinterpret_cast<const f16x4*>(&in[(long)(r0 + r) * C + c0 + c4]);
    t[r][c4] = v[0]; t[r][c4 + 1] = v[1]; t[r][c4 + 2] = v[2]; t[r][c4 + 3] = v[3];
  }
  __syncthreads();
  {
    int c = tid >> 3, r4 = (tid & 7) << 2;
    f16x4 o = {t[r4][c], t[r4 + 1][c], t[r4 + 2][c], t[r4 + 3][c]};
    *reinterpret_cast<f16x4*>(&out[(long)(c0 + c) * R + r0 + r4]) = o;
  }
}

// ---------------------------------- GEMM -----------------------------------
// C[M,N] = A[M,K] @ B^T[N,K]. 128x128 tile, BK=64, 4 waves, fp16 MFMA.
template <int CMODE>
__global__ __launch_bounds__(256) void k_gemm(const _Float16* __restrict__ A,
                                              const _Float16* __restrict__ B,
                                              float* __restrict__ Cf,
                                              _Float16* __restrict__ Ch,
                                              int M, int N, int K) {
  __shared__ alignas(16) _Float16 As[128 * 64];
  __shared__ alignas(16) _Float16 Bs[128 * 64];
  const int tid = threadIdx.x;
  const int lane = tid & 63;
  const int w = tid >> 6;
  const int wr = ((w >> 1) & 1) << 6, wc = (w & 1) << 6;
  const int bm = blockIdx.x << 7, bn = blockIdx.y << 7;
  const int g = lane >> 4, ln15 = lane & 15;

  f32x4 acc[4][4] = {};

  const int srowl = lane >> 3;
  const int skcol = (lane & 7) << 3;
  const int wofs = (srowl << 6) + (((lane & 7) ^ srowl) << 3);

  f16x8 ra[4], rb[4];
  auto loadregs = [&](int k0) {
#pragma unroll
    for (int i = 0; i < 4; ++i) {
      int ch = (w << 2) + i;
      int row = (ch << 3) + srowl;
      ra[i] = *reinterpret_cast<const f16x8*>(&A[(long)(bm + row) * K + k0 + skcol]);
      rb[i] = *reinterpret_cast<const f16x8*>(&B[(long)(bn + row) * K + k0 + skcol]);
    }
  };
  loadregs(0);
  const int nk = K >> 6;
  for (int kt = 0; kt < nk; ++kt) {
    __syncthreads();
#pragma unroll
    for (int i = 0; i < 4; ++i) {
      int ch = (w << 2) + i;
      *reinterpret_cast<f16x8*>(&As[(ch << 9) + wofs]) = ra[i];
      *reinterpret_cast<f16x8*>(&Bs[(ch << 9) + wofs]) = rb[i];
    }
    __syncthreads();
    if (kt + 1 < nk) loadregs((kt + 1) << 6);
#pragma unroll
    for (int ks = 0; ks < 2; ++ks) {
      f16x8 af[4], bf[4];
#pragma unroll
      for (int i = 0; i < 4; ++i) {
        const int arow = wr + (i << 4) + ln15;
        const int brow = wc + (i << 4) + ln15;
        const int inner = (((ks << 5) + (g << 3)) ^ ((ln15 & 7) << 3));
        af[i] = *reinterpret_cast<const f16x8*>(&As[arow * 64 + inner]);
        bf[i] = *reinterpret_cast<const f16x8*>(&Bs[brow * 64 + inner]);
      }
#pragma unroll
      for (int i = 0; i < 4; ++i)
#pragma unroll
        for (int j = 0; j < 4; ++j)
          acc[i][j] = __builtin_amdgcn_mfma_f32_16x16x32_f16(af[i], bf[j], acc[i][j], 0, 0, 0);
    }
  }
#pragma unroll
  for (int i = 0; i < 4; ++i) {
    const int row = bm + wr + (i << 4) + (g << 2);
#pragma unroll
    for (int j = 0; j < 4; ++j) {
      const int col = bn + wc + (j << 4) + ln15;
#pragma unroll
      for (int r = 0; r < 4; ++r) {
        float v = acc[i][j][r];
        long orow = row + r;
        if constexpr (CMODE == 2) {
          long m2 = ((orow >> 12) << 13) + 4096 + (orow & 4095);
          Cf[m2 * 512 + col] = v;
          Ch[m2 * 512 + col] = (_Float16)v;
        } else if constexpr (CMODE == 1) {
          Ch[orow * N + col] = (_Float16)v;
        } else {
          Cf[orow * N + col] = v;
        }
      }
    }
  }
}

// ------------------------------- attention ---------------------------------
// Split-T flash: grid (128 q-tiles, 4 T-splits, 2 batches), 4 waves/block.
// Per block: 32 Q rows (in regs), T-range of 2048 in tiles of 32.
// Emits unnormalized partial O (fp16) + per-row m,l (f32); k_comb merges.
__global__ __launch_bounds__(256) void k_attn(const _Float16* __restrict__ lq,    // (8192,512)
                                              const _Float16* __restrict__ lkv,   // (16384,512)
                                              const _Float16* __restrict__ lkvT,  // (512,16384)
                                              _Float16* __restrict__ Op,          // (8, 4096, 512)
                                              float* __restrict__ Mp,             // (8, 4096)
                                              float* __restrict__ Lp) {           // (8, 4096)
  __shared__ alignas(16) _Float16 vt_s[4 * 4104];   // [t-chunk][row^swz] 16B slots
  __shared__ alignas(16) float S_s[32 * 36];
  __shared__ alignas(16) _Float16 P_s[32 * 40];
  __shared__ float m_s[32], l_s[32], corr_s[32];

  const int tid = threadIdx.x, lane = tid & 63, w = tid >> 6;
  const int b = blockIdx.z, sp = blockIdx.y;
  const int qloc = blockIdx.x << 5;
  const long qrow = (long)b * 4096 + qloc;
  const int g = lane >> 4, ln15 = lane & 15;
  const int r0 = ((w >> 1) & 1) << 4, c0 = (w & 1) << 4;

  // Q tile in registers: lane holds row r0+ln15, elems (g*8) + 32k, k=0..15
  f16x8 qreg[16];
  {
    const _Float16* qp = lq + (qrow + r0 + ln15) * 512 + (g << 3);
#pragma unroll
    for (int kk = 0; kk < 16; ++kk)
      qreg[kk] = *reinterpret_cast<const f16x8*>(qp + (kk << 5));
  }
  if (tid < 32) { m_s[tid] = -__builtin_inff(); l_s[tid] = 0.f; }

  f32x4 acc[2][8] = {};
  const _Float16* lkv_b = lkv + (long)b * 8192 * 512;
  const int tbase = sp << 11;

  for (int it = 0; it < 64; ++it) {
    const int t0 = tbase + (it << 5);
    // --- V^T tile into regs (LDS write after barrier)
    f16x8 rv[8];
#pragma unroll
    for (int i = 0; i < 8; ++i) {
      int ch = (w << 3) + i;
      int lrow = (ch << 4) + (lane >> 2);
      rv[i] = *reinterpret_cast<const f16x8*>(
          &lkvT[(long)lrow * 16384 + (long)b * 8192 + t0 + ((lane & 3) << 3)]);
    }
    // --- S quarter = Q[16 rows] · K[16 rows]^T, K-dim 512
    f32x4 sa = {0.f, 0.f, 0.f, 0.f};
    const _Float16* kb = lkv_b + (long)(t0 + c0 + ln15) * 512 + (g << 3);
#pragma unroll
    for (int kk = 0; kk < 16; ++kk) {
      f16x8 bb = *reinterpret_cast<const f16x8*>(kb + (kk << 5));
      sa = __builtin_amdgcn_mfma_f32_16x16x32_f16(qreg[kk], bb, sa, 0, 0, 0);
    }
    __syncthreads();  // prev PV done with vt_s/P_s; prev softmax done with S_s
    // --- write V^T tile: plane c = lane&3 (t-chunk), slot = lrow ^ (c<<2)
    {
      const int c = lane & 3;
#pragma unroll
      for (int i = 0; i < 8; ++i) {
        int ch = (w << 3) + i;
        int lrow = (ch << 4) + (lane >> 2);
        *reinterpret_cast<f16x8*>(&vt_s[c * 4104 + ((lrow ^ (c << 2)) << 3)]) = rv[i];
      }
    }
    const float scale = 0.044194173824159216f;  // 1/sqrt(512)
#pragma unroll
    for (int r = 0; r < 4; ++r)
      S_s[(r0 + (g << 2) + r) * 36 + c0 + ln15] = sa[r] * scale;
    __syncthreads();
    // --- online softmax: 8 lanes per row, 4 cols each
    {
      const int row = tid >> 3, cc = (tid & 7) << 2;
      f32x4 sv = *reinterpret_cast<const f32x4*>(&S_s[row * 36 + cc]);
      float mx = fmaxf(fmaxf(sv[0], sv[1]), fmaxf(sv[2], sv[3]));
      mx = fmaxf(mx, __shfl_xor(mx, 1));
      mx = fmaxf(mx, __shfl_xor(mx, 2));
      mx = fmaxf(mx, __shfl_xor(mx, 4));
      const float mold = m_s[row];
      const float mnew = fmaxf(mold, mx);
      float p0 = __expf(sv[0] - mnew), p1 = __expf(sv[1] - mnew);
      float p2 = __expf(sv[2] - mnew), p3 = __expf(sv[3] - mnew);
      float sum = p0 + p1 + p2 + p3;
      sum += __shfl_xor(sum, 1);
      sum += __shfl_xor(sum, 2);
      sum += __shfl_xor(sum, 4);
      if ((tid & 7) == 0) {
        const float corr = __expf(mold - mnew);
        m_s[row] = mnew;
        l_s[row] = l_s[row] * corr + sum;
        corr_s[row] = corr;
      }
      f16x4 ph = {(_Float16)p0, (_Float16)p1, (_Float16)p2, (_Float16)p3};
      *reinterpret_cast<f16x4*>(&P_s[row * 40 + cc]) = ph;
    }
    __syncthreads();
    // --- rescale + PV: wave owns ctx cols [w*128, w*128+128)
    float cr0[4], cr1[4];
#pragma unroll
    for (int r = 0; r < 4; ++r) {
      cr0[r] = corr_s[(g << 2) + r];
      cr1[r] = corr_s[16 + (g << 2) + r];
    }
#pragma unroll
    for (int j = 0; j < 8; ++j)
#pragma unroll
      for (int r = 0; r < 4; ++r) {
        acc[0][j][r] *= cr0[r];
        acc[1][j][r] *= cr1[r];
      }
    f16x8 pa0 = *reinterpret_cast<const f16x8*>(&P_s[ln15 * 40 + (g << 3)]);
    f16x8 pa1 = *reinterpret_cast<const f16x8*>(&P_s[(16 + ln15) * 40 + (g << 3)]);
#pragma unroll
    for (int j = 0; j < 8; ++j) {
      const int vrow = (w << 7) + (j << 4) + ln15;
      f16x8 vb = *reinterpret_cast<const f16x8*>(
          &vt_s[g * 4104 + ((vrow ^ (g << 2)) << 3)]);
      acc[0][j] = __builtin_amdgcn_mfma_f32_16x16x32_f16(pa0, vb, acc[0][j], 0, 0, 0);
      acc[1][j] = __builtin_amdgcn_mfma_f32_16x16x32_f16(pa1, vb, acc[1][j], 0, 0, 0);
    }
  }
  // --- epilogue: unnormalized partial O + m,l
  const long pbase = ((long)((b << 2) + sp) << 12) + qloc;
#pragma unroll
  for (int j = 0; j < 8; ++j) {
    const int colb = (w << 7) + (j << 4) + ln15;
#pragma unroll
    for (int r = 0; r < 4; ++r) {
      Op[(pbase + (g << 2) + r) * 512 + colb] = (_Float16)acc[0][j][r];
      Op[(pbase + 16 + (g << 2) + r) * 512 + colb] = (_Float16)acc[1][j][r];
    }
  }
  if (tid < 32) {
    Mp[pbase + tid] = m_s[tid];
    Lp[pbase + tid] = l_s[tid];
  }
}

// --------------------------- split-KV combine ------------------------------
// ctx[r, :] = ( sum_i Op_i[r,:] * e^{m_i - M} ) / ( sum_i l_i * e^{m_i - M} )
__global__ __launch_bounds__(256) void k_comb(const _Float16* __restrict__ Op,
                                              const float* __restrict__ Mp,
                                              const float* __restrict__ Lp,
                                              _Float16* __restrict__ ctx) {
  const int r = (blockIdx.x << 3) + (threadIdx.x >> 5);  // 0..8191
  const int b = r >> 12, s = r & 4095;
  const int c0 = (threadIdx.x & 31) << 4;
  float mi[4], sc[4];
  float M = -__builtin_inff();
#pragma unroll
  for (int i = 0; i < 4; ++i) {
    mi[i] = Mp[(((b << 2) + i) << 12) + s];
    M = fmaxf(M, mi[i]);
  }
  float l = 0.f;
#pragma unroll
  for (int i = 0; i < 4; ++i) {
    sc[i] = __expf(mi[i] - M);
    l += Lp[(((b << 2) + i) << 12) + s] * sc[i];
  }
  const float inv = 1.f / l;
#pragma unroll
  for (int h = 0; h < 2; ++h) {
    f32x8 a = {0.f, 0.f, 0.f, 0.f, 0.f, 0.f, 0.f, 0.f};
#pragma unroll
    for (int i = 0; i < 4; ++i) {
      f16x8 v = *reinterpret_cast<const f16x8*>(
          &Op[((((long)((b << 2) + i) << 12) + s) * 512) + c0 + (h << 3)]);
      a += __builtin_convertvector(v, f32x8) * sc[i];
    }
    a *= inv;
    *reinterpret_cast<f16x8*>(&ctx[(long)r * 512 + c0 + (h << 3)]) =
        __builtin_convertvector(a, f16x8);
  }
}

// ------------------------------- launcher ----------------------------------

extern "C" void kernel_launch(void* const* d_in, const int* in_sizes, int n_in,
                              void* d_out, int out_size, void* d_ws, size_t ws_size,
                              hipStream_t stream) {
  const float* x     = (const float*)d_in[0];
  const float* cache = (const float*)d_in[1];
  const float* W_kv  = (const float*)d_in[2];
  const float* W_q   = (const float*)d_in[3];
  const float* W_lq  = (const float*)d_in[4];
  const float* W_o   = (const float*)d_in[5];

  float* out     = (float*)d_out;                 // (8192, 2048) f32
  float* lkv_out = out + (size_t)8192 * 2048;     // (2, 8192, 512) f32

  // scratch overlay in d_out's "out" region (dead before final GEMM writes it)
  _Float16* x16    = (_Float16*)d_out;            // 16,777,216 elems
  _Float16* lq16   = x16 + 16777216;              //  4,194,304
  _Float16* Wq16   = lq16 + 4194304;              //  4,194,304  (original (d,e) layout)
  _Float16* WlqT   = Wq16 + 4194304;              //  1,048,576
  _Float16* WcombT = WlqT + 1048576;              //  1,048,576
  _Float16* WkvT   = WcombT + 1048576;            //  1,048,576  (ends at 28,311,552 fp16)
  _Float16* Op     = x16;                         // partial O overlays x16 (dead by attn)
  float*    Mp     = (float*)d_out + 14155776;    // bytes 56.6MB.. (spare out region)
  float*    Lp     = Mp + 32768;

  // ws: buffers that survive into the final GEMM / attention (44.0 MB)
  _Float16* lkv16 = (_Float16*)d_ws;              //  8,388,608
  _Float16* lkvT  = lkv16 + 8388608;              //  8,388,608
  _Float16* ctx   = lkvT + 8388608;               //  4,194,304
  _Float16* WoT   = ctx + 4194304;                //  1,048,576

  // converts / transposes
  k_cvt<<<1024, 256, 0, stream>>>(x, x16, 16777216 / 4);
  k_cache<<<1024, 256, 0, stream>>>(cache, lkv_out, lkv16, 4194304 / 4);
  k_tc<<<dim3(16, 64), 256, 0, stream>>>(W_kv, WkvT, 2048, 512);
  k_cvt<<<1024, 256, 0, stream>>>(W_q, Wq16, 4194304 / 4);
  k_tc<<<dim3(16, 64), 256, 0, stream>>>(W_lq, WlqT, 2048, 512);
  k_tc<<<dim3(64, 16), 256, 0, stream>>>(W_o, WoT, 512, 2048);

  // l_kv_new = x @ W_kv  -> f32 l_kv rows + fp16 copy (row remap)
  k_gemm<2><<<dim3(64, 4), 256, 0, stream>>>(x16, WkvT, lkv_out, lkv16, 8192, 512, 2048);
  // W_comb^T[l][d] = sum_e WlqT[l][e] * Wq16[d][e]
  k_gemm<1><<<dim3(4, 16), 256, 0, stream>>>(WlqT, Wq16, nullptr, WcombT, 512, 2048, 2048);
  // lq = x @ W_comb
  k_gemm<1><<<dim3(64, 4), 256, 0, stream>>>(x16, WcombT, nullptr, lq16, 8192, 512, 2048);
  // l_kv^T for the PV operand
  k_tb<<<dim3(16, 512), 256, 0, stream>>>(lkv16, lkvT, 16384, 512);
  // flash attention, split-T x4 -> partials
  k_attn<<<dim3(128, 4, 2), 256, 0, stream>>>(lq16, lkv16, lkvT, Op, Mp, Lp);
  // merge partials -> ctx (fp16)
  k_comb<<<1024, 256, 0, stream>>>(Op, Mp, Lp, ctx);
  // out = ctx @ W_o
  k_gemm<0><<<dim3(64, 16), 256, 0, stream>>>(ctx, WoT, out, nullptr, 8192, 2048, 512);
}

// Round 4
// 482.314 us; speedup vs baseline: 2.0479x; 2.0479x over previous
//
#include <hip/hip_runtime.h>
#include <hip/hip_bf16.h>
#include <math.h>

// ---------------------------------------------------------------------------
// MHLA: out, l_kv = MLA(x, cache, W_kv, W_q, W_lq, W_o)
//   l_kv_new = x @ W_kv ; lq = x @ (W_q @ W_lq) * 1/sqrt(512)  [folded+scaled]
//   l_kv = concat(cache, l_kv_new)
//   S = lq @ l_kv^T  (fp16, materialized in chunks);  P = softmax_rows(S)
//   ctx = P @ l_kv ;  out = ctx @ W_o
// All matmuls on fp16 MFMA (f32 accum). Attention = GEMM + row-softmax + GEMM
// (round-3's flash kernel was latency-bound at 6% MFMA util; replaced).
// ---------------------------------------------------------------------------

typedef _Float16 f16x8 __attribute__((ext_vector_type(8)));
typedef _Float16 f16x4 __attribute__((ext_vector_type(4)));
typedef float    f32x4 __attribute__((ext_vector_type(4)));
typedef float    f32x8 __attribute__((ext_vector_type(8)));

// ---------------------------- elementwise converts -------------------------

__global__ __launch_bounds__(256) void k_cvt(const float* __restrict__ in,
                                             _Float16* __restrict__ out, int n4) {
  int i = blockIdx.x * blockDim.x + threadIdx.x;
  int st = gridDim.x * blockDim.x;
  for (; i < n4; i += st) {
    f32x4 v = reinterpret_cast<const f32x4*>(in)[i];
    reinterpret_cast<f16x4*>(out)[i] = __builtin_convertvector(v, f16x4);
  }
}

// cache (2,4096,512) -> l_kv f32 out rows [b*8192 + t] and fp16 copy
__global__ __launch_bounds__(256) void k_cache(const float* __restrict__ cache,
                                               float* __restrict__ lkv_f32,
                                               _Float16* __restrict__ lkv16, int n4) {
  int i = blockIdx.x * blockDim.x + threadIdx.x;
  int st = gridDim.x * blockDim.x;
  for (; i < n4; i += st) {
    f32x4 v = reinterpret_cast<const f32x4*>(cache)[i];
    int e = i << 2;
    int b = e >> 21;                 // 4096*512 = 2^21
    int dst = e + (b << 21);         // batch stride in l_kv is 2^22
    *reinterpret_cast<f32x4*>(lkv_f32 + dst) = v;
    *reinterpret_cast<f16x4*>(lkv16 + dst) = __builtin_convertvector(v, f16x4);
  }
}

// transpose+convert: in f32 (R x C) -> out fp16 (C x R)
__global__ __launch_bounds__(256) void k_tc(const float* __restrict__ in,
                                            _Float16* __restrict__ out, int R, int C) {
  __shared__ float t[32][33];
  const int c0 = blockIdx.x << 5, r0 = blockIdx.y << 5;
  const int tid = threadIdx.x;
  {
    int r = tid >> 3, c4 = (tid & 7) << 2;
    f32x4 v = *reinterpret_cast<const f32x4*>(&in[(long)(r0 + r) * C + c0 + c4]);
    t[r][c4] = v[0]; t[r][c4 + 1] = v[1]; t[r][c4 + 2] = v[2]; t[r][c4 + 3] = v[3];
  }
  __syncthreads();
  {
    int c = tid >> 3, r4 = (tid & 7) << 2;
    f16x4 o = {(_Float16)t[r4][c], (_Float16)t[r4 + 1][c],
               (_Float16)t[r4 + 2][c], (_Float16)t[r4 + 3][c]};
    *reinterpret_cast<f16x4*>(&out[(long)(c0 + c) * R + r0 + r4]) = o;
  }
}

// transpose fp16: in (R x C) -> out (C x R)
__global__ __launch_bounds__(256) void k_tb(const _Float16* __restrict__ in,
                                            _Float16* __restrict__ out, int R, int C) {
  __shared__ _Float16 t[32][36];
  const int c0 = blockIdx.x << 5, r0 = blockIdx.y << 5;
  const int tid = threadIdx.x;
  {
    int r = tid >> 3, c4 = (tid & 7) << 2;
    f16x4 v = *reinterpret_cast<const f16x4*>(&in[(long)(r0 + r) * C + c0 + c4]);
    t[r][c4] = v[0]; t[r][c4 + 1] = v[1]; t[r][c4 + 2] = v[2]; t[r][c4 + 3] = v[3];
  }
  __syncthreads();
  {
    int c = tid >> 3, r4 = (tid & 7) << 2;
    f16x4 o = {t[r4][c], t[r4 + 1][c], t[r4 + 2][c], t[r4 + 3][c]};
    *reinterpret_cast<f16x4*>(&out[(long)(c0 + c) * R + r0 + r4]) = o;
  }
}

// ---------------------------------- GEMM -----------------------------------
// C[M,N] = A[M,K] @ B^T  where B is [N][ldb] with the K values k-contiguous.
// 128x128 tile, BK=64, 4 waves, fp16 MFMA, reg-staged, XOR-swizzled LDS.
// CMODE: 0 = f32 C ; 1 = fp16 C ; 2 = f32+fp16 C with l_kv row remap ;
//        3 = fp16 C scaled by cscale.
template <int CMODE>
__global__ __launch_bounds__(256) void k_gemm(const _Float16* __restrict__ A,
                                              const _Float16* __restrict__ B,
                                              float* __restrict__ Cf,
                                              _Float16* __restrict__ Ch,
                                              int M, int N, int K, int ldb,
                                              float cscale) {
  __shared__ alignas(16) _Float16 As[128 * 64];
  __shared__ alignas(16) _Float16 Bs[128 * 64];
  const int tid = threadIdx.x;
  const int lane = tid & 63;
  const int w = tid >> 6;
  const int wr = ((w >> 1) & 1) << 6, wc = (w & 1) << 6;
  const int bm = blockIdx.x << 7, bn = blockIdx.y << 7;
  const int g = lane >> 4, ln15 = lane & 15;

  f32x4 acc[4][4] = {};

  const int srowl = lane >> 3;
  const int skcol = (lane & 7) << 3;
  const int wofs = (srowl << 6) + (((lane & 7) ^ srowl) << 3);

  f16x8 ra[4], rb[4];
  auto loadregs = [&](int k0) {
#pragma unroll
    for (int i = 0; i < 4; ++i) {
      int ch = (w << 2) + i;
      int row = (ch << 3) + srowl;
      ra[i] = *reinterpret_cast<const f16x8*>(&A[(long)(bm + row) * K + k0 + skcol]);
      rb[i] = *reinterpret_cast<const f16x8*>(&B[(long)(bn + row) * ldb + k0 + skcol]);
    }
  };
  loadregs(0);
  const int nk = K >> 6;
  for (int kt = 0; kt < nk; ++kt) {
    __syncthreads();
#pragma unroll
    for (int i = 0; i < 4; ++i) {
      int ch = (w << 2) + i;
      *reinterpret_cast<f16x8*>(&As[(ch << 9) + wofs]) = ra[i];
      *reinterpret_cast<f16x8*>(&Bs[(ch << 9) + wofs]) = rb[i];
    }
    __syncthreads();
    if (kt + 1 < nk) loadregs((kt + 1) << 6);
#pragma unroll
    for (int ks = 0; ks < 2; ++ks) {
      f16x8 af[4], bf[4];
#pragma unroll
      for (int i = 0; i < 4; ++i) {
        const int arow = wr + (i << 4) + ln15;
        const int brow = wc + (i << 4) + ln15;
        const int inner = (((ks << 5) + (g << 3)) ^ ((ln15 & 7) << 3));
        af[i] = *reinterpret_cast<const f16x8*>(&As[arow * 64 + inner]);
        bf[i] = *reinterpret_cast<const f16x8*>(&Bs[brow * 64 + inner]);
      }
#pragma unroll
      for (int i = 0; i < 4; ++i)
#pragma unroll
        for (int j = 0; j < 4; ++j)
          acc[i][j] = __builtin_amdgcn_mfma_f32_16x16x32_f16(af[i], bf[j], acc[i][j], 0, 0, 0);
    }
  }
#pragma unroll
  for (int i = 0; i < 4; ++i) {
    const int row = bm + wr + (i << 4) + (g << 2);
#pragma unroll
    for (int j = 0; j < 4; ++j) {
      const int col = bn + wc + (j << 4) + ln15;
#pragma unroll
      for (int r = 0; r < 4; ++r) {
        float v = acc[i][j][r];
        long orow = row + r;
        if constexpr (CMODE == 2) {
          long m2 = ((orow >> 12) << 13) + 4096 + (orow & 4095);
          Cf[m2 * 512 + col] = v;
          Ch[m2 * 512 + col] = (_Float16)v;
        } else if constexpr (CMODE == 1) {
          Ch[orow * N + col] = (_Float16)v;
        } else if constexpr (CMODE == 3) {
          Ch[orow * N + col] = (_Float16)(v * cscale);
        } else {
          Cf[orow * N + col] = v;
        }
      }
    }
  }
}

// ------------------------------- row softmax --------------------------------
// One block per row of 8192 fp16; in-place normalized softmax.
__global__ __launch_bounds__(256) void k_smax(_Float16* __restrict__ S) {
  const int tid = threadIdx.x;
  _Float16* row = S + ((long)blockIdx.x << 13);
  __shared__ float red[4];
  f16x8 v[4];
#pragma unroll
  for (int c = 0; c < 4; ++c)
    v[c] = *reinterpret_cast<const f16x8*>(row + (c << 11) + (tid << 3));
  float mx = -1e30f;
#pragma unroll
  for (int c = 0; c < 4; ++c) {
    f32x8 f = __builtin_convertvector(v[c], f32x8);
#pragma unroll
    for (int j = 0; j < 8; ++j) mx = fmaxf(mx, f[j]);
  }
#pragma unroll
  for (int o = 32; o > 0; o >>= 1) mx = fmaxf(mx, __shfl_xor(mx, o));
  if ((tid & 63) == 0) red[tid >> 6] = mx;
  __syncthreads();
  mx = fmaxf(fmaxf(red[0], red[1]), fmaxf(red[2], red[3]));
  float sum = 0.f;
  f32x8 p0, p1, p2, p3;
  {
    f32x8 f;
#define SMAX_EXP(PC, CI)                                         \
    f = __builtin_convertvector(v[CI], f32x8);                   \
    _Pragma("unroll")                                            \
    for (int j = 0; j < 8; ++j) { PC[j] = __expf(f[j] - mx); sum += PC[j]; }
    SMAX_EXP(p0, 0) SMAX_EXP(p1, 1) SMAX_EXP(p2, 2) SMAX_EXP(p3, 3)
#undef SMAX_EXP
  }
#pragma unroll
  for (int o = 32; o > 0; o >>= 1) sum += __shfl_xor(sum, o);
  __syncthreads();
  if ((tid & 63) == 0) red[tid >> 6] = sum;
  __syncthreads();
  const float inv = 1.f / (red[0] + red[1] + red[2] + red[3]);
  *reinterpret_cast<f16x8*>(row + (0 << 11) + (tid << 3)) = __builtin_convertvector(p0 * inv, f16x8);
  *reinterpret_cast<f16x8*>(row + (1 << 11) + (tid << 3)) = __builtin_convertvector(p1 * inv, f16x8);
  *reinterpret_cast<f16x8*>(row + (2 << 11) + (tid << 3)) = __builtin_convertvector(p2 * inv, f16x8);
  *reinterpret_cast<f16x8*>(row + (3 << 11) + (tid << 3)) = __builtin_convertvector(p3 * inv, f16x8);
}

// ------------------------------- launcher ----------------------------------

extern "C" void kernel_launch(void* const* d_in, const int* in_sizes, int n_in,
                              void* d_out, int out_size, void* d_ws, size_t ws_size,
                              hipStream_t stream) {
  const float* x     = (const float*)d_in[0];
  const float* cache = (const float*)d_in[1];
  const float* W_kv  = (const float*)d_in[2];
  const float* W_q   = (const float*)d_in[3];
  const float* W_lq  = (const float*)d_in[4];
  const float* W_o   = (const float*)d_in[5];

  float* out     = (float*)d_out;                 // (8192, 2048) f32
  float* lkv_out = out + (size_t)8192 * 2048;     // (2, 8192, 512) f32

  // scratch overlay in d_out's "out" region (dead before final GEMM writes it)
  _Float16* base16 = (_Float16*)d_out;
  _Float16* x16    = base16;                      // [0        .. 16,777,216)
  _Float16* lq16   = base16 + 16777216;           // [16.78M   .. 20.97M)  live->S-GEMM
  _Float16* Wq16   = base16 + 20971520;           // dead after Wcomb GEMM
  _Float16* WlqT   = base16 + 25165824;           // dead after Wcomb GEMM
  _Float16* WcombT = base16 + 26214400;           // dead after lq GEMM
  _Float16* WkvT   = base16 + 27262976;           // dead after lkv GEMM (end 28.3M)
  _Float16* lkvT16 = base16 + 20971520;           // built AFTER the above die;
                                                  // spans ..29,360,128 (< 33.5M) ✓

  // ws: lkv16 16.8MB | ctx 8.4MB | WoT 2MB | S chunk
  _Float16* lkv16 = (_Float16*)d_ws;              // 8,388,608 elems
  _Float16* ctx   = lkv16 + 8388608;              // 4,194,304
  _Float16* WoT   = ctx + 4194304;                // 1,048,576
  _Float16* Sbuf  = WoT + 1048576;                // CR*8192 elems

  // S chunk rows: pick largest fitting ws_size (base usage = 27,262,976 B)
  const size_t sbase = 27262976;
  int CR = 1024;
  if (ws_size >= sbase + (size_t)4096 * 8192 * 2) CR = 4096;
  else if (ws_size >= sbase + (size_t)2048 * 8192 * 2) CR = 2048;

  const float iscale = 0.044194173824159216f;  // 1/sqrt(512)

  // converts / transposes
  k_cvt<<<1024, 256, 0, stream>>>(x, x16, 16777216 / 4);
  k_cache<<<1024, 256, 0, stream>>>(cache, lkv_out, lkv16, 4194304 / 4);
  k_tc<<<dim3(16, 64), 256, 0, stream>>>(W_kv, WkvT, 2048, 512);
  k_cvt<<<1024, 256, 0, stream>>>(W_q, Wq16, 4194304 / 4);
  k_tc<<<dim3(16, 64), 256, 0, stream>>>(W_lq, WlqT, 2048, 512);
  k_tc<<<dim3(64, 16), 256, 0, stream>>>(W_o, WoT, 512, 2048);

  // l_kv_new = x @ W_kv -> f32 l_kv rows + fp16 copy (row remap)
  k_gemm<2><<<dim3(64, 4), 256, 0, stream>>>(x16, WkvT, lkv_out, lkv16,
                                             8192, 512, 2048, 2048, 1.f);
  // W_comb^T[l][d] = sum_e WlqT[l][e]*Wq16[d][e], scaled by 1/sqrt(512)
  k_gemm<3><<<dim3(4, 16), 256, 0, stream>>>(WlqT, Wq16, nullptr, WcombT,
                                             512, 2048, 2048, 2048, iscale);
  // lq = x @ W_comb  (pre-scaled)
  k_gemm<1><<<dim3(64, 4), 256, 0, stream>>>(x16, WcombT, nullptr, lq16,
                                             8192, 512, 2048, 2048, 1.f);
  // l_kv^T (512 x 16384) into d_out spare (weights dead by now)
  k_tb<<<dim3(16, 512), 256, 0, stream>>>(lkv16, lkvT16, 16384, 512);

  // attention: per CR-row chunk (chunk lies in one batch): S-GEMM, softmax, PV
  for (long r0 = 0; r0 < 8192; r0 += CR) {
    const long b = r0 >> 12;
    // S = lq_chunk @ l_kv_b^T   (fp16, CR x 8192)
    k_gemm<1><<<dim3(CR >> 7, 64), 256, 0, stream>>>(
        lq16 + r0 * 512, lkv16 + b * 8192 * 512, nullptr, Sbuf,
        CR, 8192, 512, 512, 1.f);
    // P = softmax rows (in place, normalized)
    k_smax<<<CR, 256, 0, stream>>>(Sbuf);
    // ctx_chunk = P @ V  (B = lkvT panel of batch b, row stride 16384)
    k_gemm<1><<<dim3(CR >> 7, 4), 256, 0, stream>>>(
        Sbuf, lkvT16 + b * 8192, nullptr, ctx + r0 * 512,
        CR, 512, 8192, 16384, 1.f);
  }

  // out = ctx @ W_o
  k_gemm<0><<<dim3(64, 16), 256, 0, stream>>>(ctx, WoT, out, nullptr,
                                              8192, 2048, 512, 512, 1.f);
}

// Round 5
// 371.768 us; speedup vs baseline: 2.6569x; 1.2974x over previous
//
#include <hip/hip_runtime.h>
#include <hip/hip_bf16.h>
#include <math.h>

// ---------------------------------------------------------------------------
// MHLA: out, l_kv = MLA(x, cache, W_kv, W_q, W_lq, W_o)
//   l_kv_new = x @ W_kv ; lq = x @ (W_q @ W_lq) * 1/sqrt(512)  [folded+scaled]
//   l_kv = concat(cache, l_kv_new)
//   S = lq @ l_kv^T  (fp16, chunked);  P = softmax_rows(S)
//   ctx = P @ l_kv   [split-K x4 -> f32 partials -> reduce]
//   out = ctx @ W_o
// All matmuls on fp16 MFMA (f32 accum). d_out's "out" region doubles as
// scratch (x16 region is reused for PV split-K partials once x16 is dead).
// ---------------------------------------------------------------------------

typedef _Float16 f16x8 __attribute__((ext_vector_type(8)));
typedef _Float16 f16x4 __attribute__((ext_vector_type(4)));
typedef float    f32x4 __attribute__((ext_vector_type(4)));
typedef float    f32x8 __attribute__((ext_vector_type(8)));

// ---------------------------- elementwise converts -------------------------

__global__ __launch_bounds__(256) void k_cvt(const float* __restrict__ in,
                                             _Float16* __restrict__ out, int n4) {
  int i = blockIdx.x * blockDim.x + threadIdx.x;
  int st = gridDim.x * blockDim.x;
  for (; i < n4; i += st) {
    f32x4 v = reinterpret_cast<const f32x4*>(in)[i];
    reinterpret_cast<f16x4*>(out)[i] = __builtin_convertvector(v, f16x4);
  }
}

// cache (2,4096,512) -> l_kv f32 out rows [b*8192 + t] and fp16 copy
__global__ __launch_bounds__(256) void k_cache(const float* __restrict__ cache,
                                               float* __restrict__ lkv_f32,
                                               _Float16* __restrict__ lkv16, int n4) {
  int i = blockIdx.x * blockDim.x + threadIdx.x;
  int st = gridDim.x * blockDim.x;
  for (; i < n4; i += st) {
    f32x4 v = reinterpret_cast<const f32x4*>(cache)[i];
    int e = i << 2;
    int b = e >> 21;                 // 4096*512 = 2^21
    int dst = e + (b << 21);         // batch stride in l_kv is 2^22
    *reinterpret_cast<f32x4*>(lkv_f32 + dst) = v;
    *reinterpret_cast<f16x4*>(lkv16 + dst) = __builtin_convertvector(v, f16x4);
  }
}

// transpose+convert: in f32 (R x C) -> out fp16 (C x R)
__global__ __launch_bounds__(256) void k_tc(const float* __restrict__ in,
                                            _Float16* __restrict__ out, int R, int C) {
  __shared__ float t[32][33];
  const int c0 = blockIdx.x << 5, r0 = blockIdx.y << 5;
  const int tid = threadIdx.x;
  {
    int r = tid >> 3, c4 = (tid & 7) << 2;
    f32x4 v = *reinterpret_cast<const f32x4*>(&in[(long)(r0 + r) * C + c0 + c4]);
    t[r][c4] = v[0]; t[r][c4 + 1] = v[1]; t[r][c4 + 2] = v[2]; t[r][c4 + 3] = v[3];
  }
  __syncthreads();
  {
    int c = tid >> 3, r4 = (tid & 7) << 2;
    f16x4 o = {(_Float16)t[r4][c], (_Float16)t[r4 + 1][c],
               (_Float16)t[r4 + 2][c], (_Float16)t[r4 + 3][c]};
    *reinterpret_cast<f16x4*>(&out[(long)(c0 + c) * R + r0 + r4]) = o;
  }
}

// transpose fp16: in (R x C) -> out (C x R)
__global__ __launch_bounds__(256) void k_tb(const _Float16* __restrict__ in,
                                            _Float16* __restrict__ out, int R, int C) {
  __shared__ _Float16 t[32][36];
  const int c0 = blockIdx.x << 5, r0 = blockIdx.y << 5;
  const int tid = threadIdx.x;
  {
    int r = tid >> 3, c4 = (tid & 7) << 2;
    f16x4 v = *reinterpret_cast<const f16x4*>(&in[(long)(r0 + r) * C + c0 + c4]);
    t[r][c4] = v[0]; t[r][c4 + 1] = v[1]; t[r][c4 + 2] = v[2]; t[r][c4 + 3] = v[3];
  }
  __syncthreads();
  {
    int c = tid >> 3, r4 = (tid & 7) << 2;
    f16x4 o = {t[r4][c], t[r4 + 1][c], t[r4 + 2][c], t[r4 + 3][c]};
    *reinterpret_cast<f16x4*>(&out[(long)(c0 + c) * R + r0 + r4]) = o;
  }
}

// ---------------------------------- GEMM -----------------------------------
// C[M,N] = A[M,K] @ B^T where A is [M][lda], B is [N][ldb] (K-contig rows).
// 128x128 tile, BK=64, 4 waves, fp16 MFMA, reg-staged, XOR-swizzled LDS.
// CMODE: 0 = f32 C ; 1 = fp16 C ; 2 = f32+fp16 C with l_kv row remap ;
//        3 = fp16 C scaled ; 4 = split-K f32 partial (blockIdx.z = K-slice,
//            K is the per-slice depth, Cf has M*N stride per slice).
template <int CMODE>
__global__ __launch_bounds__(256) void k_gemm(const _Float16* __restrict__ A,
                                              const _Float16* __restrict__ B,
                                              float* __restrict__ Cf,
                                              _Float16* __restrict__ Ch,
                                              int M, int N, int K, int lda, int ldb,
                                              float cscale) {
  if constexpr (CMODE == 4) {
    const long z = blockIdx.z;
    A += z * K;                // K-slice offset within row (lda is full stride)
    B += z * K;
    Cf += z * (long)M * N;
  }
  __shared__ alignas(16) _Float16 As[128 * 64];
  __shared__ alignas(16) _Float16 Bs[128 * 64];
  const int tid = threadIdx.x;
  const int lane = tid & 63;
  const int w = tid >> 6;
  const int wr = ((w >> 1) & 1) << 6, wc = (w & 1) << 6;
  const int bm = blockIdx.x << 7, bn = blockIdx.y << 7;
  const int g = lane >> 4, ln15 = lane & 15;

  f32x4 acc[4][4] = {};

  const int srowl = lane >> 3;
  const int skcol = (lane & 7) << 3;
  const int wofs = (srowl << 6) + (((lane & 7) ^ srowl) << 3);

  f16x8 ra[4], rb[4];
  auto loadregs = [&](int k0) {
#pragma unroll
    for (int i = 0; i < 4; ++i) {
      int ch = (w << 2) + i;
      int row = (ch << 3) + srowl;
      ra[i] = *reinterpret_cast<const f16x8*>(&A[(long)(bm + row) * lda + k0 + skcol]);
      rb[i] = *reinterpret_cast<const f16x8*>(&B[(long)(bn + row) * ldb + k0 + skcol]);
    }
  };
  loadregs(0);
  const int nk = K >> 6;
  for (int kt = 0; kt < nk; ++kt) {
    __syncthreads();
#pragma unroll
    for (int i = 0; i < 4; ++i) {
      int ch = (w << 2) + i;
      *reinterpret_cast<f16x8*>(&As[(ch << 9) + wofs]) = ra[i];
      *reinterpret_cast<f16x8*>(&Bs[(ch << 9) + wofs]) = rb[i];
    }
    __syncthreads();
    if (kt + 1 < nk) loadregs((kt + 1) << 6);
#pragma unroll
    for (int ks = 0; ks < 2; ++ks) {
      f16x8 af[4], bf[4];
#pragma unroll
      for (int i = 0; i < 4; ++i) {
        const int arow = wr + (i << 4) + ln15;
        const int brow = wc + (i << 4) + ln15;
        const int inner = (((ks << 5) + (g << 3)) ^ ((ln15 & 7) << 3));
        af[i] = *reinterpret_cast<const f16x8*>(&As[arow * 64 + inner]);
        bf[i] = *reinterpret_cast<const f16x8*>(&Bs[brow * 64 + inner]);
      }
#pragma unroll
      for (int i = 0; i < 4; ++i)
#pragma unroll
        for (int j = 0; j < 4; ++j)
          acc[i][j] = __builtin_amdgcn_mfma_f32_16x16x32_f16(af[i], bf[j], acc[i][j], 0, 0, 0);
    }
  }
#pragma unroll
  for (int i = 0; i < 4; ++i) {
    const int row = bm + wr + (i << 4) + (g << 2);
#pragma unroll
    for (int j = 0; j < 4; ++j) {
      const int col = bn + wc + (j << 4) + ln15;
#pragma unroll
      for (int r = 0; r < 4; ++r) {
        float v = acc[i][j][r];
        long orow = row + r;
        if constexpr (CMODE == 2) {
          long m2 = ((orow >> 12) << 13) + 4096 + (orow & 4095);
          Cf[m2 * 512 + col] = v;
          Ch[m2 * 512 + col] = (_Float16)v;
        } else if constexpr (CMODE == 1) {
          Ch[orow * N + col] = (_Float16)v;
        } else if constexpr (CMODE == 3) {
          Ch[orow * N + col] = (_Float16)(v * cscale);
        } else {  // 0 and 4
          Cf[orow * N + col] = v;
        }
      }
    }
  }
}

// --------------------- split-K reduce: sum 4 slices -> fp16 -----------------
__global__ __launch_bounds__(256) void k_red4(const float* __restrict__ p,
                                              _Float16* __restrict__ o,
                                              int n4, float scale) {
  const f32x4* pv = reinterpret_cast<const f32x4*>(p);
  int i = blockIdx.x * blockDim.x + threadIdx.x;
  int st = gridDim.x * blockDim.x;
  for (; i < n4; i += st) {
    f32x4 a = pv[i] + pv[i + n4] + pv[i + 2 * n4] + pv[i + 3 * n4];
    a *= scale;
    reinterpret_cast<f16x4*>(o)[i] = __builtin_convertvector(a, f16x4);
  }
}

// ------------------------------- row softmax --------------------------------
// One block per row of 8192 fp16; in-place normalized softmax.
__global__ __launch_bounds__(256) void k_smax(_Float16* __restrict__ S) {
  const int tid = threadIdx.x;
  _Float16* row = S + ((long)blockIdx.x << 13);
  __shared__ float red[4];
  f16x8 v[4];
#pragma unroll
  for (int c = 0; c < 4; ++c)
    v[c] = *reinterpret_cast<const f16x8*>(row + (c << 11) + (tid << 3));
  float mx = -1e30f;
#pragma unroll
  for (int c = 0; c < 4; ++c) {
    f32x8 f = __builtin_convertvector(v[c], f32x8);
#pragma unroll
    for (int j = 0; j < 8; ++j) mx = fmaxf(mx, f[j]);
  }
#pragma unroll
  for (int o = 32; o > 0; o >>= 1) mx = fmaxf(mx, __shfl_xor(mx, o));
  if ((tid & 63) == 0) red[tid >> 6] = mx;
  __syncthreads();
  mx = fmaxf(fmaxf(red[0], red[1]), fmaxf(red[2], red[3]));
  float sum = 0.f;
  f32x8 p0, p1, p2, p3;
  {
    f32x8 f;
#define SMAX_EXP(PC, CI)                                         \
    f = __builtin_convertvector(v[CI], f32x8);                   \
    _Pragma("unroll")                                            \
    for (int j = 0; j < 8; ++j) { PC[j] = __expf(f[j] - mx); sum += PC[j]; }
    SMAX_EXP(p0, 0) SMAX_EXP(p1, 1) SMAX_EXP(p2, 2) SMAX_EXP(p3, 3)
#undef SMAX_EXP
  }
#pragma unroll
  for (int o = 32; o > 0; o >>= 1) sum += __shfl_xor(sum, o);
  __syncthreads();
  if ((tid & 63) == 0) red[tid >> 6] = sum;
  __syncthreads();
  const float inv = 1.f / (red[0] + red[1] + red[2] + red[3]);
  *reinterpret_cast<f16x8*>(row + (0 << 11) + (tid << 3)) = __builtin_convertvector(p0 * inv, f16x8);
  *reinterpret_cast<f16x8*>(row + (1 << 11) + (tid << 3)) = __builtin_convertvector(p1 * inv, f16x8);
  *reinterpret_cast<f16x8*>(row + (2 << 11) + (tid << 3)) = __builtin_convertvector(p2 * inv, f16x8);
  *reinterpret_cast<f16x8*>(row + (3 << 11) + (tid << 3)) = __builtin_convertvector(p3 * inv, f16x8);
}

// ------------------------------- launcher ----------------------------------

extern "C" void kernel_launch(void* const* d_in, const int* in_sizes, int n_in,
                              void* d_out, int out_size, void* d_ws, size_t ws_size,
                              hipStream_t stream) {
  const float* x     = (const float*)d_in[0];
  const float* cache = (const float*)d_in[1];
  const float* W_kv  = (const float*)d_in[2];
  const float* W_q   = (const float*)d_in[3];
  const float* W_lq  = (const float*)d_in[4];
  const float* W_o   = (const float*)d_in[5];

  float* out     = (float*)d_out;                 // (8192, 2048) f32
  float* lkv_out = out + (size_t)8192 * 2048;     // (2, 8192, 512) f32

  // scratch overlay in d_out's "out" region (dead before final GEMM writes it)
  _Float16* base16 = (_Float16*)d_out;
  _Float16* x16    = base16;                      // [0        .. 16,777,216)
  _Float16* lq16   = base16 + 16777216;           // [16.78M   .. 20.97M) live->S-GEMM
  _Float16* Wq16   = base16 + 20971520;           // dead after Wcomb GEMM
  _Float16* WlqT   = base16 + 25165824;           // dead after Wcomb GEMM
  _Float16* WcombT = base16 + 26214400;           // dead after lq GEMM
  _Float16* WkvT   = base16 + 27262976;           // dead after lkv GEMM (end 28.3M)
  _Float16* lkvT16 = base16 + 20971520;           // built AFTER the above die;
                                                  // spans ..29,360,128 (< 33.5M) ✓
  float*    PVp    = (float*)d_out;               // PV split-K partials overlay x16
                                                  // (4 * CR * 512 f32 <= 33.5 MB) ✓

  // ws: lkv16 16.8MB | ctx 8.4MB | WoT 2MB | S chunk
  _Float16* lkv16 = (_Float16*)d_ws;              // 8,388,608 elems
  _Float16* ctx   = lkv16 + 8388608;              // 4,194,304
  _Float16* WoT   = ctx + 4194304;                // 1,048,576
  _Float16* Sbuf  = WoT + 1048576;                // CR*8192 elems
  float*    Wcp   = (float*)Sbuf;                 // Wcomb split-K partials (16.8MB,
                                                  // dead before S-GEMM writes Sbuf)

  // S chunk rows: pick largest fitting ws_size (base usage = 27,262,976 B)
  const size_t sbase = 27262976;
  int CR = 1024;
  if (ws_size >= sbase + (size_t)4096 * 8192 * 2) CR = 4096;
  else if (ws_size >= sbase + (size_t)2048 * 8192 * 2) CR = 2048;

  const float iscale = 0.044194173824159216f;  // 1/sqrt(512)

  // converts / transposes
  k_cvt<<<1024, 256, 0, stream>>>(x, x16, 16777216 / 4);
  k_cache<<<1024, 256, 0, stream>>>(cache, lkv_out, lkv16, 4194304 / 4);
  k_tc<<<dim3(16, 64), 256, 0, stream>>>(W_kv, WkvT, 2048, 512);
  k_cvt<<<1024, 256, 0, stream>>>(W_q, Wq16, 4194304 / 4);
  k_tc<<<dim3(16, 64), 256, 0, stream>>>(W_lq, WlqT, 2048, 512);
  k_tc<<<dim3(64, 16), 256, 0, stream>>>(W_o, WoT, 512, 2048);

  // l_kv_new = x @ W_kv -> f32 l_kv rows + fp16 copy (row remap)
  k_gemm<2><<<dim3(64, 4), 256, 0, stream>>>(x16, WkvT, lkv_out, lkv16,
                                             8192, 512, 2048, 2048, 2048, 1.f);
  // W_comb^T[l][d] = sum_e WlqT[l][e]*Wq16[d][e] : split-K x4 + scaled reduce
  k_gemm<4><<<dim3(4, 16, 4), 256, 0, stream>>>(WlqT, Wq16, Wcp, nullptr,
                                                512, 2048, 512, 2048, 2048, 1.f);
  k_red4<<<1024, 256, 0, stream>>>(Wcp, WcombT, (512 * 2048) / 4, iscale);
  // lq = x @ W_comb  (pre-scaled)
  k_gemm<1><<<dim3(64, 4), 256, 0, stream>>>(x16, WcombT, nullptr, lq16,
                                             8192, 512, 2048, 2048, 2048, 1.f);
  // l_kv^T (512 x 16384) into d_out spare (weights dead by now)
  k_tb<<<dim3(16, 512), 256, 0, stream>>>(lkv16, lkvT16, 16384, 512);

  // attention per CR-row chunk (chunk lies in one batch): S, softmax, PV
  for (long r0 = 0; r0 < 8192; r0 += CR) {
    const long b = r0 >> 12;
    // S = lq_chunk @ l_kv_b^T   (fp16, CR x 8192)
    k_gemm<1><<<dim3(CR >> 7, 64), 256, 0, stream>>>(
        lq16 + r0 * 512, lkv16 + b * 8192 * 512, nullptr, Sbuf,
        CR, 8192, 512, 512, 512, 1.f);
    // P = softmax rows (in place, normalized)
    k_smax<<<CR, 256, 0, stream>>>(Sbuf);
    // ctx_chunk = P @ V : split-K x4 (Ks=2048) -> f32 partials -> reduce
    k_gemm<4><<<dim3(CR >> 7, 4, 4), 256, 0, stream>>>(
        Sbuf, lkvT16 + b * 8192, PVp, nullptr,
        CR, 512, 2048, 8192, 16384, 1.f);
    k_red4<<<2048, 256, 0, stream>>>(PVp, ctx + r0 * 512, (CR * 512) / 4, 1.f);
  }

  // out = ctx @ W_o
  k_gemm<0><<<dim3(64, 16), 256, 0, stream>>>(ctx, WoT, out, nullptr,
                                              8192, 2048, 512, 512, 512, 1.f);
}